// Round 3
// baseline (881.258 us; speedup 1.0000x reference)
//
#include <hip/hip_runtime.h>

#define NS 6
#define NXD 3
#define NC 8
#define NR 64
#define NB 36          // S * 2 * XD
#define NPOINTS 262144
#define OUTD 288       // C * NB
#define PTS 32         // points per block

typedef float vfloat4 __attribute__((ext_vector_type(4)));  // native vector: OK for nontemporal builtin

__device__ __forceinline__ unsigned short f2bf(float f) {
    unsigned u = __float_as_uint(f);
    unsigned r = u + 0x7fffu + ((u >> 16) & 1u);   // round-to-nearest-even
    return (unsigned short)(r >> 16);
}
__device__ __forceinline__ unsigned pack2(float a, float b) {
    return (unsigned)f2bf(a) | ((unsigned)f2bf(b) << 16);
}

// ---------- QUAD layout: pxq[b][y][x][c] = uint2{pack2(v00,v01), pack2(v10,v11)} ----------
// One 8B load per bilinear sample; 8 c-lanes of a point = one 64B line.
__global__ void build_pxq(const float* __restrict__ F2, uint2* __restrict__ pxq) {
    int tid = blockIdx.x * 256 + threadIdx.x;   // total = 36*64*64*8 = 1,179,648
    int c  = tid & 7;
    int xx = (tid >> 3) & 63;
    int y  = (tid >> 9) & 63;
    int b  = tid >> 15;
    const float* img = F2 + (size_t)(b * NC + c) * NR * NR;
    int x1 = xx < 63 ? xx + 1 : 63;
    int y1 = y  < 63 ? y  + 1 : 63;
    float v00 = img[y  * 64 + xx], v01 = img[y  * 64 + x1];
    float v10 = img[y1 * 64 + xx], v11 = img[y1 * 64 + x1];
    pxq[tid] = make_uint2(pack2(v00, v01), pack2(v10, v11));
}

// ---------- fallback layout (fits 4.9 MB): px65[b][y(65)][x][c] = pack2(v[y][x], v[y][x+1]) ----------
__global__ void build_px65(const float* __restrict__ F2, unsigned* __restrict__ px) {
    int tid = blockIdx.x * 256 + threadIdx.x;   // total = 36*65*64*8
    const int total = NB * 65 * 64 * NC;
    if (tid >= total) return;
    int c  = tid & 7;
    int xx = (tid >> 3) & 63;
    int rest = tid >> 9;          // b*65 + y
    int y = rest % 65;
    int b = rest / 65;
    int ys = y < 63 ? y : 63;
    const float* src = F2 + (((size_t)(b * NC + c) * NR + ys) * NR);
    float v0 = src[xx];
    float v1 = src[xx < 63 ? xx + 1 : 63];
    px[tid] = pack2(v0, v1);
}

// f1q[b][y][c] = pack2(f1[y], f1[min(y+1,63)]), f1[y] = 0.5*(col31+col32)  (gx=0 -> wx=0.5)
__global__ void build_f1q(const float* __restrict__ F, unsigned* __restrict__ f1q) {
    int tid = blockIdx.x * 256 + threadIdx.x;
    const int total = NB * 64 * NC;
    if (tid >= total) return;
    int c = tid & 7;
    int y = (tid >> 3) & 63;
    int b = tid >> 9;
    const float* img = F + (size_t)(b * NC + c) * NR * NR;
    float a = 0.5f * (img[y * NR + 31] + img[y * NR + 32]);
    int y1 = y < 63 ? y + 1 : 63;
    float bb = 0.5f * (img[y1 * NR + 31] + img[y1 * NR + 32]);
    f1q[tid] = pack2(a, bb);
}

template <bool QUAD>
__global__ __launch_bounds__(256) void encode_kernel(
    const float* __restrict__ x,
    const void* __restrict__ pxv,
    const unsigned* __restrict__ f1q,
    float* __restrict__ out)
{
    const int t = threadIdx.x;
    const int c = t & 7;                  // channel lane
    const int u = t >> 3;                 // point within tile
    const int n = blockIdx.x * PTS + u;

    const float xv0 = x[3 * n + 0];
    const float xv1 = x[3 * n + 1];
    const float xv2 = x[3 * n + 2];

    float o[NB];

    #pragma unroll
    for (int g = 0; g < 12; ++g) {        // (s,p) groups; each group of 3 b's is self-contained
        const int s = g >> 1;
        const int p = g & 1;
        const float sc = (float)(1 << s);
        float l0, l1, l2;
        if (p == 0) { l0 = __sinf(xv0 * sc); l1 = __sinf(xv1 * sc); l2 = __sinf(xv2 * sc); }
        else        { l0 = __cosf(xv0 * sc); l1 = __cosf(xv1 * sc); l2 = __cosf(xv2 * sc); }
        const float la[3] = {l0, l1, l2};
        #pragma unroll
        for (int k = 0; k < 3; ++k) {
            const int b = g * 3 + k;
            const float gy1 = la[k];
            const float ga  = la[k == 0 ? 1 : (k == 1 ? 2 : 0)];   // pairs[k][0]
            const float gb  = la[k == 0 ? 2 : (k == 1 ? 0 : 1)];   // pairs[k][1]

            // fs: 1-D lerp (wx=0.5 folded into f1q)
            float fy  = fminf(fmaxf(__builtin_fmaf(gy1, 31.5f, 31.5f), 0.0f), 63.0f);
            float fy0 = floorf(fy);
            float wy  = fy - fy0;
            int   y0  = (int)fy0;
            unsigned pr = f1q[(b * 64 + y0) * 8 + c];
            float a0 = __uint_as_float(pr << 16);
            float a1 = __uint_as_float(pr & 0xffff0000u);
            float fsv = __builtin_fmaf(a1 - a0, wy, a0);

            // fs2: bilinear
            float fx2 = fminf(fmaxf(__builtin_fmaf(ga, 31.5f, 31.5f), 0.0f), 63.0f);
            float fyy = fminf(fmaxf(__builtin_fmaf(gb, 31.5f, 31.5f), 0.0f), 63.0f);
            float fx0 = floorf(fx2), fyy0 = floorf(fyy);
            float wx  = fx2 - fx0,   wy2  = fyy - fyy0;
            int   xx  = (int)fx0,    yy   = (int)fyy0;

            unsigned qx, qy;
            if (QUAD) {
                const uint2* pxq = (const uint2*)pxv;
                uint2 q = pxq[b * 32768 + (yy * 64 + xx) * 8 + c];
                qx = q.x; qy = q.y;
            } else {
                const unsigned* px = (const unsigned*)pxv;
                const unsigned* rb = px + ((b * 65 + yy) * 64 + xx) * 8 + c;
                qx = rb[0];
                qy = rb[512];
            }
            float v00 = __uint_as_float(qx << 16);
            float v01 = __uint_as_float(qx & 0xffff0000u);
            float v10 = __uint_as_float(qy << 16);
            float v11 = __uint_as_float(qy & 0xffff0000u);
            float tp   = __builtin_fmaf(v01 - v00, wx, v00);
            float bt   = __builtin_fmaf(v11 - v10, wx, v10);
            float fs2v = __builtin_fmaf(bt - tp, wy2, tp);

            o[b] = __builtin_fmaf(fsv, fs2v, gy1);
        }
    }

    // thread (n,c) owns 36 consecutive output floats: out[n*288 + c*36 .. +35]
    // (36*c is a multiple of 4 -> 16B aligned). Nontemporal: don't evict gather tables from L2.
    vfloat4* ob = (vfloat4*)(out + (size_t)n * OUTD + c * 36);
    #pragma unroll
    for (int q = 0; q < 9; ++q) {
        vfloat4 v = {o[4 * q + 0], o[4 * q + 1], o[4 * q + 2], o[4 * q + 3]};
        __builtin_nontemporal_store(v, ob + q);
    }
}

extern "C" void kernel_launch(void* const* d_in, const int* in_sizes, int n_in,
                              void* d_out, int out_size, void* d_ws, size_t ws_size,
                              hipStream_t stream)
{
    const float* x  = (const float*)d_in[0];
    const float* F  = (const float*)d_in[1];
    const float* F2 = (const float*)d_in[2];
    float* out = (float*)d_out;

    const size_t quad_bytes = (size_t)NB * 64 * 64 * NC * 8 + (size_t)NB * 64 * NC * 4; // 9.51 MB

    if (ws_size >= quad_bytes) {
        uint2* pxq    = (uint2*)d_ws;                        // 36*64*64*8 uint2 = 9.44 MB
        unsigned* f1q = (unsigned*)(pxq + NB * 64 * 64 * NC);
        build_pxq<<<NB * 64 * 64 * NC / 256, 256, 0, stream>>>(F2, pxq);
        build_f1q<<<(NB * 64 * NC + 255) / 256, 256, 0, stream>>>(F, f1q);
        encode_kernel<true><<<NPOINTS / PTS, 256, 0, stream>>>(x, pxq, f1q, out);
    } else {
        unsigned* px  = (unsigned*)d_ws;                     // 36*65*64*8 uint = 4.79 MB
        unsigned* f1q = px + NB * 65 * 64 * NC;
        build_px65<<<(NB * 65 * 64 * NC + 255) / 256, 256, 0, stream>>>(F2, px);
        build_f1q<<<(NB * 64 * NC + 255) / 256, 256, 0, stream>>>(F, f1q);
        encode_kernel<false><<<NPOINTS / PTS, 256, 0, stream>>>(x, px, f1q, out);
    }
}

// Round 4
// 488.489 us; speedup vs baseline: 1.8040x; 1.8040x over previous
//
#include <hip/hip_runtime.h>

#define NS 6
#define NXD 3
#define NC 8
#define NR 64
#define NB 36          // S * 2 * XD
#define NPOINTS 262144
#define OUTD 288       // C * NB
#define PTS 32         // points per block

__device__ __forceinline__ unsigned short f2bf(float f) {
    unsigned u = __float_as_uint(f);
    unsigned r = u + 0x7fffu + ((u >> 16) & 1u);   // round-to-nearest-even
    return (unsigned short)(r >> 16);
}
__device__ __forceinline__ unsigned pack2(float a, float b) {
    return (unsigned)f2bf(a) | ((unsigned)f2bf(b) << 16);
}

#define PXQ_BLOCKS (NB * 64 * 64 * NC / 256)   // 4608
#define F1Q_BLOCKS (NB * 64 * NC / 256)        // 72

// Fused table build.
// pxq[b][y][x][c] = uint2{pack2(v00,v01), pack2(v10,v11)}: one 8B load per bilinear
// sample; the 8 c-lanes of a point fetch exactly one 64B line.
// f1q[b][y][c] = pack2(f1[y], f1[y+1]), f1[y]=0.5*(col31+col32)  (gx=0 -> wx=0.5 exact)
__global__ void build_tables(const float* __restrict__ F, const float* __restrict__ F2,
                             uint2* __restrict__ pxq, unsigned* __restrict__ f1q) {
    if (blockIdx.x < PXQ_BLOCKS) {
        int tid = blockIdx.x * 256 + threadIdx.x;   // 36*64*64*8 = 1,179,648
        int c  = tid & 7;
        int xx = (tid >> 3) & 63;
        int y  = (tid >> 9) & 63;
        int b  = tid >> 15;
        const float* img = F2 + (size_t)(b * NC + c) * NR * NR;
        int x1 = xx < 63 ? xx + 1 : 63;
        int y1 = y  < 63 ? y  + 1 : 63;
        float v00 = img[y  * 64 + xx], v01 = img[y  * 64 + x1];
        float v10 = img[y1 * 64 + xx], v11 = img[y1 * 64 + x1];
        pxq[tid] = make_uint2(pack2(v00, v01), pack2(v10, v11));
    } else {
        int tid = (blockIdx.x - PXQ_BLOCKS) * 256 + threadIdx.x;  // 36*64*8 = 18,432
        int c = tid & 7;
        int y = (tid >> 3) & 63;
        int b = tid >> 9;
        const float* img = F + (size_t)(b * NC + c) * NR * NR;
        float a = 0.5f * (img[y * NR + 31] + img[y * NR + 32]);
        int y1 = y < 63 ? y + 1 : 63;
        float bb = 0.5f * (img[y1 * NR + 31] + img[y1 * NR + 32]);
        f1q[tid] = pack2(a, bb);
    }
}

__global__ __launch_bounds__(256) void encode_kernel(
    const float* __restrict__ x,
    const uint2* __restrict__ pxq,
    const unsigned* __restrict__ f1q,
    float* __restrict__ out)
{
    const int t = threadIdx.x;
    const int c = t & 7;                  // channel lane
    const int u = t >> 3;                 // point within tile
    const int n = blockIdx.x * PTS + u;

    const float xv0 = x[3 * n + 0];
    const float xv1 = x[3 * n + 1];
    const float xv2 = x[3 * n + 2];

    float o[NB];

    #pragma unroll
    for (int g = 0; g < 12; ++g) {        // (s,p) groups; each group of 3 b's self-contained
        const int s = g >> 1;
        const int p = g & 1;
        const float sc = (float)(1 << s);
        float l0, l1, l2;
        if (p == 0) { l0 = __sinf(xv0 * sc); l1 = __sinf(xv1 * sc); l2 = __sinf(xv2 * sc); }
        else        { l0 = __cosf(xv0 * sc); l1 = __cosf(xv1 * sc); l2 = __cosf(xv2 * sc); }
        const float la[3] = {l0, l1, l2};
        #pragma unroll
        for (int k = 0; k < 3; ++k) {
            const int b = g * 3 + k;
            const float gy1 = la[k];
            const float ga  = la[k == 0 ? 1 : (k == 1 ? 2 : 0)];   // pairs[k][0]
            const float gb  = la[k == 0 ? 2 : (k == 1 ? 0 : 1)];   // pairs[k][1]

            // fs: 1-D lerp (wx=0.5 folded into f1q)
            float fy  = fminf(fmaxf(__builtin_fmaf(gy1, 31.5f, 31.5f), 0.0f), 63.0f);
            float fy0 = floorf(fy);
            float wy  = fy - fy0;
            int   y0  = (int)fy0;
            unsigned pr = f1q[(b * 64 + y0) * 8 + c];
            float a0 = __uint_as_float(pr << 16);
            float a1 = __uint_as_float(pr & 0xffff0000u);
            float fsv = __builtin_fmaf(a1 - a0, wy, a0);

            // fs2: bilinear via one 8B quad load
            float fx2 = fminf(fmaxf(__builtin_fmaf(ga, 31.5f, 31.5f), 0.0f), 63.0f);
            float fyy = fminf(fmaxf(__builtin_fmaf(gb, 31.5f, 31.5f), 0.0f), 63.0f);
            float fx0 = floorf(fx2), fyy0 = floorf(fyy);
            float wx  = fx2 - fx0,   wy2  = fyy - fyy0;
            int   xx  = (int)fx0,    yy   = (int)fyy0;

            uint2 q = pxq[b * 32768 + (yy * 64 + xx) * 8 + c];
            float v00 = __uint_as_float(q.x << 16);
            float v01 = __uint_as_float(q.x & 0xffff0000u);
            float v10 = __uint_as_float(q.y << 16);
            float v11 = __uint_as_float(q.y & 0xffff0000u);
            float tp   = __builtin_fmaf(v01 - v00, wx, v00);
            float bt   = __builtin_fmaf(v11 - v10, wx, v10);
            float fs2v = __builtin_fmaf(bt - tp, wy2, tp);

            o[b] = __builtin_fmaf(fsv, fs2v, gy1);
        }
    }

    // thread (n,c) owns 36 consecutive floats: out[n*288 + c*36 .. +35].
    // A wave's 9 float4-stores cover a contiguous 9216B region -> L2 merges
    // partial lines to full-line HBM writes (NO nontemporal: nt defeated the
    // merge in R3 and caused 3.85x write amplification).
    float4* ob = (float4*)(out + (size_t)n * OUTD + c * 36);
    #pragma unroll
    for (int q = 0; q < 9; ++q) {
        ob[q] = make_float4(o[4 * q + 0], o[4 * q + 1], o[4 * q + 2], o[4 * q + 3]);
    }
}

extern "C" void kernel_launch(void* const* d_in, const int* in_sizes, int n_in,
                              void* d_out, int out_size, void* d_ws, size_t ws_size,
                              hipStream_t stream)
{
    const float* x  = (const float*)d_in[0];
    const float* F  = (const float*)d_in[1];
    const float* F2 = (const float*)d_in[2];
    float* out = (float*)d_out;

    uint2* pxq    = (uint2*)d_ws;                        // 36*64*64*8 uint2 = 9.44 MB
    unsigned* f1q = (unsigned*)(pxq + NB * 64 * 64 * NC);

    build_tables<<<PXQ_BLOCKS + F1Q_BLOCKS, 256, 0, stream>>>(F, F2, pxq, f1q);
    encode_kernel<<<NPOINTS / PTS, 256, 0, stream>>>(x, pxq, f1q, out);
}